// Round 1
// baseline (332.832 us; speedup 1.0000x reference)
//
#include <hip/hip_runtime.h>

// BatchNeuralKB: out[b] = max_f exp(-clamp(||q_b - f||^2,0)/2)
//             = exp(-0.5 * clamp-min over f of d2(b,f))
// d2 = qsq[b] + fsq[f] - 2 * dot(q_b, fact_f), K = 384 (3 x 128 concat)
//
// Strategy: bf16 MFMA GEMM (M=2048, N=65536, K=384) with fused min epilogue.
// atomicMin on uint bit patterns (valid: all values clamped >= 0).

#define AS1 __attribute__((address_space(1)))
#define AS3 __attribute__((address_space(3)))

typedef __attribute__((ext_vector_type(8))) __bf16 bf16x8;
typedef __attribute__((ext_vector_type(4))) float f32x4;
typedef __attribute__((ext_vector_type(4))) unsigned short us4;

__device__ __forceinline__ void gl2lds16(const void* g, void* l) {
    __builtin_amdgcn_global_load_lds((const AS1 unsigned int*)g,
                                     (AS3 unsigned int*)l, 16, 0, 0);
}

// round-to-nearest-even fp32 -> bf16
__device__ __forceinline__ unsigned short f2bf(float f) {
    unsigned int u = __float_as_uint(f);
    u = (u + 0x7fffu + ((u >> 16) & 1u)) >> 16;
    return (unsigned short)u;
}

__global__ void init_min_kernel(unsigned int* ob, int n) {
    int i = blockIdx.x * blockDim.x + threadIdx.x;
    if (i < n) ob[i] = 0x7f800000u;  // +inf
}

// One wave per row: convert concat row to bf16 (optional) and compute sum-of-squares.
__global__ void conv_rows_kernel(const float* __restrict__ p0, const float* __restrict__ p1,
                                 const float* __restrict__ p2, unsigned short* __restrict__ outb,
                                 float* __restrict__ sq, int nrows) {
    const int lane = threadIdx.x & 63;
    const int wave = threadIdx.x >> 6;
    const int row = blockIdx.x * 4 + wave;
    if (row >= nrows) return;
    float s = 0.f;
#pragma unroll
    for (int c = 0; c < 6; ++c) {
        int k = c * 64 + lane;
        const float* src = (k < 128) ? p0 : (k < 256) ? p1 : p2;
        float v = src[(size_t)row * 128 + (k & 127)];
        s += v * v;
        if (outb) outb[(size_t)row * 384 + k] = f2bf(v);
    }
#pragma unroll
    for (int off = 32; off >= 1; off >>= 1) s += __shfl_xor(s, off, 64);
    if (lane == 0) sq[row] = s;
}

// 128x128 tile GEMM with fused clamp+min epilogue.
// PRE=true: facts pre-converted to bf16 (Fb). PRE=false: stage fp32 facts inline.
template <bool PRE>
__global__ __launch_bounds__(256)
void gemm_min_kernel(const unsigned short* __restrict__ Qb,  // [M][384] bf16
                     const unsigned short* __restrict__ Fb,  // [N][384] bf16 (PRE)
                     const float* __restrict__ f0, const float* __restrict__ f1,
                     const float* __restrict__ f2,           // (!PRE) fp32 fact parts
                     const float* __restrict__ qsq, const float* __restrict__ fsq,
                     unsigned int* __restrict__ outbits, int K) {
    __shared__ __align__(16) unsigned short As[128 * 32];
    __shared__ __align__(16) unsigned short Bs[128 * 32];
    __shared__ float smin[128 * 2];

    const int tid = threadIdx.x;
    const int lane = tid & 63;
    const int wid = tid >> 6;
    const int wm = wid >> 1, wn = wid & 1;
    const int col = lane & 15, quad = lane >> 4;

    const int m0 = blockIdx.x * 128;
    const int n0 = blockIdx.y * 128;

    f32x4 acc[4][4];
#pragma unroll
    for (int i = 0; i < 4; ++i)
#pragma unroll
        for (int j = 0; j < 4; ++j) {
            f32x4 z = {0.f, 0.f, 0.f, 0.f};
            acc[i][j] = z;
        }

    const int nk = K >> 5;  // 12
    for (int kk = 0; kk < nk; ++kk) {
        const int k0 = kk << 5;
        __syncthreads();  // previous iteration's LDS reads complete
        // stage A (queries, bf16): 8KB via 2x global_load_lds width-16
#pragma unroll
        for (int it = 0; it < 2; ++it) {
            int iid = it * 256 + tid;            // 0..511
            int row = iid >> 2, ch = iid & 3;    // row 0..127, 16B chunk 0..3
            gl2lds16(Qb + ((size_t)(m0 + row) * K + k0 + ch * 8),
                     As + (row * 32 + ch * 8));
        }
        if (PRE) {
#pragma unroll
            for (int it = 0; it < 2; ++it) {
                int iid = it * 256 + tid;
                int row = iid >> 2, ch = iid & 3;
                gl2lds16(Fb + ((size_t)(n0 + row) * K + k0 + ch * 8),
                         Bs + (row * 32 + ch * 8));
            }
        } else {
            const float* src = (k0 < 128) ? f0 : (k0 < 256) ? f1 : f2;
            const int kp = k0 & 127;
#pragma unroll
            for (int it = 0; it < 4; ++it) {
                int iid = it * 256 + tid;          // 0..1023
                int row = iid >> 3, ch = iid & 7;  // row 0..127, float4 chunk 0..7
                const float4 v = *(const float4*)(src + (size_t)(n0 + row) * 128 + kp + ch * 4);
                us4 w = {f2bf(v.x), f2bf(v.y), f2bf(v.z), f2bf(v.w)};
                *(us4*)(Bs + (row * 32 + ch * 4)) = w;
            }
        }
        __syncthreads();  // staging complete

        bf16x8 af[4], bf[4];
#pragma unroll
        for (int i = 0; i < 4; ++i)
            af[i] = *(const bf16x8*)(As + ((wm * 64 + i * 16 + col) * 32 + quad * 8));
#pragma unroll
        for (int j = 0; j < 4; ++j)
            bf[j] = *(const bf16x8*)(Bs + ((wn * 64 + j * 16 + col) * 32 + quad * 8));
#pragma unroll
        for (int i = 0; i < 4; ++i)
#pragma unroll
            for (int j = 0; j < 4; ++j)
                acc[i][j] = __builtin_amdgcn_mfma_f32_16x16x32_bf16(af[i], bf[j], acc[i][j], 0, 0, 0);
    }

    // Epilogue: d2 = qsq + fsq - 2*dot, clamp >= 0, min over this WG's 128 cols.
    float fs[4];
#pragma unroll
    for (int j = 0; j < 4; ++j) fs[j] = fsq[n0 + wn * 64 + j * 16 + col];

#pragma unroll
    for (int i = 0; i < 4; ++i) {
#pragma unroll
        for (int r = 0; r < 4; ++r) {
            const int mrow = wm * 64 + i * 16 + quad * 4 + r;
            const float qs = qsq[m0 + mrow];
            float mn = 3.0e38f;
#pragma unroll
            for (int j = 0; j < 4; ++j) {
                float d2 = qs + fs[j] - 2.0f * acc[i][j][r];
                d2 = fmaxf(d2, 0.0f);
                mn = fminf(mn, d2);
            }
            // min across the 16 lanes of this quad-group (covers 64 cols)
#pragma unroll
            for (int off = 1; off < 16; off <<= 1)
                mn = fminf(mn, __shfl_xor(mn, off, 64));
            if (col == 0) smin[mrow * 2 + wn] = mn;
        }
    }
    __syncthreads();
    if (tid < 128) {
        float v = fminf(smin[tid * 2 + 0], smin[tid * 2 + 1]);
        atomicMin(outbits + m0 + tid, __float_as_uint(v));
    }
}

__global__ void finalize_kernel(float* out, int n) {
    int i = blockIdx.x * blockDim.x + threadIdx.x;
    if (i < n) {
        float d2 = __uint_as_float(((unsigned int*)out)[i]);
        out[i] = expf(-0.5f * d2);
    }
}

// Emergency path (tiny ws): pure fp32 distance, 16 queries x 2048-fact chunks.
__global__ __launch_bounds__(256)
void tier3_kernel(const float* __restrict__ rel, const float* __restrict__ a1,
                  const float* __restrict__ a2, const float* __restrict__ fr,
                  const float* __restrict__ fa1, const float* __restrict__ fa2,
                  unsigned int* __restrict__ outbits) {
    __shared__ float qs[16][384];
    __shared__ float red[4][16];
    const int tid = threadIdx.x;
    const int qbase = blockIdx.y * 16;
    const int fbase = blockIdx.x * 2048;
    for (int i = tid; i < 16 * 384; i += 256) {
        int r = i / 384, c = i % 384;
        const float* src = (c < 128) ? rel : (c < 256) ? a1 : a2;
        qs[r][c] = src[(size_t)(qbase + r) * 128 + (c & 127)];
    }
    __syncthreads();
    float mn[16];
#pragma unroll
    for (int q = 0; q < 16; ++q) mn[q] = 3.0e38f;
    for (int fi = 0; fi < 2048; fi += 256) {
        const int f = fbase + fi + tid;
        float acc[16];
#pragma unroll
        for (int q = 0; q < 16; ++q) acc[q] = 0.f;
#pragma unroll
        for (int p = 0; p < 3; ++p) {
            const float* fp = ((p == 0) ? fr : (p == 1) ? fa1 : fa2) + (size_t)f * 128;
            for (int k4 = 0; k4 < 32; ++k4) {
                const float4 fv = *(const float4*)(fp + k4 * 4);
#pragma unroll
                for (int q = 0; q < 16; ++q) {
                    float d0 = fv.x - qs[q][p * 128 + k4 * 4 + 0];
                    float d1 = fv.y - qs[q][p * 128 + k4 * 4 + 1];
                    float d2 = fv.z - qs[q][p * 128 + k4 * 4 + 2];
                    float d3 = fv.w - qs[q][p * 128 + k4 * 4 + 3];
                    acc[q] += d0 * d0 + d1 * d1 + d2 * d2 + d3 * d3;
                }
            }
        }
#pragma unroll
        for (int q = 0; q < 16; ++q) mn[q] = fminf(mn[q], fmaxf(acc[q], 0.f));
    }
#pragma unroll
    for (int q = 0; q < 16; ++q) {
        float v = mn[q];
#pragma unroll
        for (int off = 32; off >= 1; off >>= 1) v = fminf(v, __shfl_xor(v, off, 64));
        if ((tid & 63) == 0) red[tid >> 6][q] = v;
    }
    __syncthreads();
    if (tid < 16) {
        float v = fminf(fminf(red[0][tid], red[1][tid]), fminf(red[2][tid], red[3][tid]));
        atomicMin(outbits + qbase + tid, __float_as_uint(v));
    }
}

extern "C" void kernel_launch(void* const* d_in, const int* in_sizes, int n_in,
                              void* d_out, int out_size, void* d_ws, size_t ws_size,
                              hipStream_t stream) {
    const float* rel = (const float*)d_in[0];
    const float* a1 = (const float*)d_in[1];
    const float* a2 = (const float*)d_in[2];
    const float* fr = (const float*)d_in[3];
    const float* fa1 = (const float*)d_in[4];
    const float* fa2 = (const float*)d_in[5];

    const int E = 128, K = 384;
    const int B = in_sizes[0] / E;   // 2048
    const int F = in_sizes[3] / E;   // 65536

    float* out = (float*)d_out;
    unsigned int* outbits = (unsigned int*)d_out;

    const size_t fb_bytes = (size_t)F * K * 2;   // 48 MB facts bf16
    const size_t qb_bytes = (size_t)B * K * 2;   // 1.5 MB queries bf16
    const size_t need_full = fb_bytes + qb_bytes + (size_t)F * 4 + (size_t)B * 4;
    const size_t need_lean = qb_bytes + (size_t)F * 4 + (size_t)B * 4;

    init_min_kernel<<<(B + 255) / 256, 256, 0, stream>>>(outbits, B);

    if (ws_size >= need_full) {
        unsigned short* Fb = (unsigned short*)d_ws;
        unsigned short* Qb = (unsigned short*)((char*)d_ws + fb_bytes);
        float* fsq = (float*)((char*)d_ws + fb_bytes + qb_bytes);
        float* qsq = fsq + F;
        conv_rows_kernel<<<B / 4, 256, 0, stream>>>(rel, a1, a2, Qb, qsq, B);
        conv_rows_kernel<<<F / 4, 256, 0, stream>>>(fr, fa1, fa2, Fb, fsq, F);
        gemm_min_kernel<true><<<dim3(B / 128, F / 128), 256, 0, stream>>>(
            Qb, Fb, nullptr, nullptr, nullptr, qsq, fsq, outbits, K);
    } else if (ws_size >= need_lean) {
        unsigned short* Qb = (unsigned short*)d_ws;
        float* fsq = (float*)((char*)d_ws + qb_bytes);
        float* qsq = fsq + F;
        conv_rows_kernel<<<B / 4, 256, 0, stream>>>(rel, a1, a2, Qb, qsq, B);
        conv_rows_kernel<<<F / 4, 256, 0, stream>>>(fr, fa1, fa2, nullptr, fsq, F);
        gemm_min_kernel<false><<<dim3(B / 128, F / 128), 256, 0, stream>>>(
            Qb, nullptr, fr, fa1, fa2, qsq, fsq, outbits, K);
    } else {
        tier3_kernel<<<dim3(F / 2048, B / 16), 256, 0, stream>>>(rel, a1, a2, fr, fa1, fa2, outbits);
    }

    finalize_kernel<<<(B + 255) / 256, 256, 0, stream>>>(out, B);
}

// Round 2
// 240.159 us; speedup vs baseline: 1.3859x; 1.3859x over previous
//
#include <hip/hip_runtime.h>

// BatchNeuralKB: out[b] = max_f exp(-clamp(||q_b - f||^2,0)/2)
//             = exp(-0.5 * clamp(qsq[b] + min_f(fsq[f] - 2*dot(q_b,f)), 0))
// bf16 MFMA GEMM M=2048, N=65536, K=384 with fused register-resident min.
//
// FULL path: 128(m) x 256(n) WG tile, wave tile 64x128 (4x8 16x16x32 MFMAs),
// BK=96, WG iterates 8 n-tiles; LDS XOR-swizzled via pre-swizzled workspace
// (global_load_lds LDS side is wave-linear, global side is per-lane -> swizzle
// must live in the global layout). atomicMin on uint bits of clamped d2 (>=0).

#define AS1 __attribute__((address_space(1)))
#define AS3 __attribute__((address_space(3)))

typedef __attribute__((ext_vector_type(8))) __bf16 bf16x8;
typedef __attribute__((ext_vector_type(4))) float f32x4;
typedef __attribute__((ext_vector_type(4))) unsigned short us4;

__device__ __forceinline__ void gl2lds16(const void* g, void* l) {
    __builtin_amdgcn_global_load_lds((const AS1 unsigned int*)g,
                                     (AS3 unsigned int*)l, 16, 0, 0);
}

// round-to-nearest-even fp32 -> bf16
__device__ __forceinline__ unsigned short f2bf(float f) {
    unsigned int u = __float_as_uint(f);
    u = (u + 0x7fffu + ((u >> 16) & 1u)) >> 16;
    return (unsigned short)u;
}

__global__ void init_min_kernel(unsigned int* ob, int n) {
    int i = blockIdx.x * blockDim.x + threadIdx.x;
    if (i < n) ob[i] = 0x7f800000u;  // +inf
}

// ---------- FULL path: swizzled bf16 conversion ----------
// Row layout: 12 groups of 32 halfwords; within each group the four 8-hw
// chunks are stored at position c' = c ^ s(row), s(row)=(row&3)^((row>>2)&3).
__global__ void conv_swz_kernel(const float* __restrict__ p0, const float* __restrict__ p1,
                                const float* __restrict__ p2, unsigned short* __restrict__ outb,
                                float* __restrict__ sq, int nrows) {
    const int lane = threadIdx.x & 63;
    const int wave = threadIdx.x >> 6;
    const int row = blockIdx.x * 4 + wave;
    if (row >= nrows) return;
    float s = 0.f;
    if (lane < 48) {
        const int p = lane >> 4;            // concat part 0..2
        const int off = (lane & 15) * 8;    // elem offset within part
        const float* src = ((p == 0) ? p0 : (p == 1) ? p1 : p2) + (size_t)row * 128 + off;
        const float4 v0 = *(const float4*)(src);
        const float4 v1 = *(const float4*)(src + 4);
        s = v0.x * v0.x + v0.y * v0.y + v0.z * v0.z + v0.w * v0.w +
            v1.x * v1.x + v1.y * v1.y + v1.z * v1.z + v1.w * v1.w;
        const int k = p * 128 + off;            // multiple of 8
        const int g = k >> 5;                   // 32-hw group
        const int c = (k >> 3) & 3;             // chunk within group
        const int sw = (row & 3) ^ ((row >> 2) & 3);
        unsigned short* dst = outb + (size_t)row * 384 + g * 32 + ((c ^ sw) * 8);
        us4 w0 = {f2bf(v0.x), f2bf(v0.y), f2bf(v0.z), f2bf(v0.w)};
        us4 w1 = {f2bf(v1.x), f2bf(v1.y), f2bf(v1.z), f2bf(v1.w)};
        *(us4*)(dst) = w0;
        *(us4*)(dst + 4) = w1;
    }
#pragma unroll
    for (int off = 32; off >= 1; off >>= 1) s += __shfl_xor(s, off, 64);
    if (lane == 0) sq[row] = s;
}

// ---------- FULL GEMM: 128x256 WG tile, 8 n-tiles per WG ----------
__global__ __launch_bounds__(256, 2)
void gemm_full_kernel(const unsigned short* __restrict__ Qb,  // [M][384] bf16 swizzled
                      const unsigned short* __restrict__ Fb,  // [N][384] bf16 swizzled
                      const float* __restrict__ qsq, const float* __restrict__ fsq,
                      unsigned int* __restrict__ outbits, int ntiles) {
    __shared__ __align__(16) unsigned short As[3 * 128 * 32];  // 24 KB (BK=96)
    __shared__ __align__(16) unsigned short Bs[3 * 256 * 32];  // 48 KB
    __shared__ float smin[128][2];

    const int tid = threadIdx.x;
    const int lane = tid & 63;
    const int wid = tid >> 6;
    const int wm = wid >> 1, wn = wid & 1;
    const int col = lane & 15, quad = lane >> 4;
    // read-side swizzle: row mod 16 == col for every fragment row we touch
    const int swz = ((quad ^ (col & 3) ^ ((col >> 2) & 3)) * 8);

    const int m0 = blockIdx.y * 128;
    const int K = 384;

    float rowmin[16];
#pragma unroll
    for (int v = 0; v < 16; ++v) rowmin[v] = 3.0e38f;

    for (int t = 0; t < ntiles; ++t) {
        const int n0 = (blockIdx.x * ntiles + t) * 256;
        f32x4 acc[4][8];
#pragma unroll
        for (int i = 0; i < 4; ++i)
#pragma unroll
            for (int j = 0; j < 8; ++j) {
                f32x4 z = {0.f, 0.f, 0.f, 0.f};
                acc[i][j] = z;
            }

        for (int kk = 0; kk < 4; ++kk) {  // K=384 in BK=96 chunks
            const int kbase = kk * 96;
            __syncthreads();  // prior LDS reads complete
            // stage A: 24KB = 6 insts; LDS linear in iid (hardware requirement)
#pragma unroll
            for (int it = 0; it < 6; ++it) {
                int iid = it * 256 + tid;                   // 0..1535
                int sub = iid >> 9, row = (iid >> 2) & 127, ch = iid & 3;
                gl2lds16(Qb + ((size_t)(m0 + row) * K + kbase + sub * 32 + ch * 8),
                         As + (size_t)iid * 8);
            }
            // stage B: 48KB = 12 insts
#pragma unroll
            for (int it = 0; it < 12; ++it) {
                int iid = it * 256 + tid;                   // 0..3071
                int sub = iid >> 10, row = (iid >> 2) & 255, ch = iid & 3;
                gl2lds16(Fb + ((size_t)(n0 + row) * K + kbase + sub * 32 + ch * 8),
                         Bs + (size_t)iid * 8);
            }
            __syncthreads();  // staging visible

#pragma unroll
            for (int sub = 0; sub < 3; ++sub) {
                bf16x8 af[4], bfv[8];
#pragma unroll
                for (int i = 0; i < 4; ++i)
                    af[i] = *(const bf16x8*)(As + (sub * 128 + wm * 64 + i * 16 + col) * 32 + swz);
#pragma unroll
                for (int j = 0; j < 8; ++j)
                    bfv[j] = *(const bf16x8*)(Bs + (sub * 256 + wn * 128 + j * 16 + col) * 32 + swz);
#pragma unroll
                for (int i = 0; i < 4; ++i)
#pragma unroll
                    for (int j = 0; j < 8; ++j)
                        acc[i][j] = __builtin_amdgcn_mfma_f32_16x16x32_bf16(af[i], bfv[j], acc[i][j], 0, 0, 0);
            }
        }

        // fold this tile into register-resident row minima: min_f(fsq - 2*dot)
        float fs[8];
#pragma unroll
        for (int j = 0; j < 8; ++j) fs[j] = fsq[n0 + wn * 128 + j * 16 + col];
#pragma unroll
        for (int i = 0; i < 4; ++i)
#pragma unroll
            for (int r = 0; r < 4; ++r) {
                float mn = rowmin[i * 4 + r];
#pragma unroll
                for (int j = 0; j < 8; ++j)
                    mn = fminf(mn, fmaf(-2.0f, acc[i][j][r], fs[j]));
                rowmin[i * 4 + r] = mn;
            }
    }

    // once per WG: cross-lane (16 cols) min, combine halves, atomic merge
#pragma unroll
    for (int v = 0; v < 16; ++v) {
        float mn = rowmin[v];
#pragma unroll
        for (int off = 1; off < 16; off <<= 1) mn = fminf(mn, __shfl_xor(mn, off, 64));
        rowmin[v] = mn;
    }
    if (col == 0) {
#pragma unroll
        for (int i = 0; i < 4; ++i)
#pragma unroll
            for (int r = 0; r < 4; ++r)
                smin[wm * 64 + i * 16 + quad * 4 + r][wn] = rowmin[i * 4 + r];
    }
    __syncthreads();
    if (tid < 128) {
        float d = fminf(smin[tid][0], smin[tid][1]);
        float d2 = fmaxf(qsq[m0 + tid] + d, 0.0f);
        atomicMin(outbits + m0 + tid, __float_as_uint(d2));
    }
}

__global__ void finalize_kernel(float* out, int n) {
    int i = blockIdx.x * blockDim.x + threadIdx.x;
    if (i < n) {
        float d2 = __uint_as_float(((unsigned int*)out)[i]);
        out[i] = expf(-0.5f * d2);
    }
}

// ---------- LEAN fallback (previous round's verified kernel) ----------
__global__ void conv_rows_kernel(const float* __restrict__ p0, const float* __restrict__ p1,
                                 const float* __restrict__ p2, unsigned short* __restrict__ outb,
                                 float* __restrict__ sq, int nrows) {
    const int lane = threadIdx.x & 63;
    const int wave = threadIdx.x >> 6;
    const int row = blockIdx.x * 4 + wave;
    if (row >= nrows) return;
    float s = 0.f;
#pragma unroll
    for (int c = 0; c < 6; ++c) {
        int k = c * 64 + lane;
        const float* src = (k < 128) ? p0 : (k < 256) ? p1 : p2;
        float v = src[(size_t)row * 128 + (k & 127)];
        s += v * v;
        if (outb) outb[(size_t)row * 384 + k] = f2bf(v);
    }
#pragma unroll
    for (int off = 32; off >= 1; off >>= 1) s += __shfl_xor(s, off, 64);
    if (lane == 0) sq[row] = s;
}

__global__ __launch_bounds__(256)
void gemm_lean_kernel(const unsigned short* __restrict__ Qb,
                      const float* __restrict__ f0, const float* __restrict__ f1,
                      const float* __restrict__ f2,
                      const float* __restrict__ qsq, const float* __restrict__ fsq,
                      unsigned int* __restrict__ outbits, int K) {
    __shared__ __align__(16) unsigned short As[128 * 32];
    __shared__ __align__(16) unsigned short Bs[128 * 32];
    __shared__ float smin[128 * 2];

    const int tid = threadIdx.x;
    const int lane = tid & 63;
    const int wid = tid >> 6;
    const int wm = wid >> 1, wn = wid & 1;
    const int col = lane & 15, quad = lane >> 4;
    const int m0 = blockIdx.x * 128;
    const int n0 = blockIdx.y * 128;

    f32x4 acc[4][4];
#pragma unroll
    for (int i = 0; i < 4; ++i)
#pragma unroll
        for (int j = 0; j < 4; ++j) {
            f32x4 z = {0.f, 0.f, 0.f, 0.f};
            acc[i][j] = z;
        }

    const int nk = K >> 5;
    for (int kk = 0; kk < nk; ++kk) {
        const int k0 = kk << 5;
        __syncthreads();
#pragma unroll
        for (int it = 0; it < 2; ++it) {
            int iid = it * 256 + tid;
            int row = iid >> 2, ch = iid & 3;
            gl2lds16(Qb + ((size_t)(m0 + row) * K + k0 + ch * 8), As + (row * 32 + ch * 8));
        }
        const float* src = (k0 < 128) ? f0 : (k0 < 256) ? f1 : f2;
        const int kp = k0 & 127;
#pragma unroll
        for (int it = 0; it < 4; ++it) {
            int iid = it * 256 + tid;
            int row = iid >> 3, ch = iid & 7;
            const float4 v = *(const float4*)(src + (size_t)(n0 + row) * 128 + kp + ch * 4);
            us4 w = {f2bf(v.x), f2bf(v.y), f2bf(v.z), f2bf(v.w)};
            *(us4*)(Bs + (row * 32 + ch * 4)) = w;
        }
        __syncthreads();

        bf16x8 af[4], bfv[4];
#pragma unroll
        for (int i = 0; i < 4; ++i)
            af[i] = *(const bf16x8*)(As + ((wm * 64 + i * 16 + col) * 32 + quad * 8));
#pragma unroll
        for (int j = 0; j < 4; ++j)
            bfv[j] = *(const bf16x8*)(Bs + ((wn * 64 + j * 16 + col) * 32 + quad * 8));
#pragma unroll
        for (int i = 0; i < 4; ++i)
#pragma unroll
            for (int j = 0; j < 4; ++j)
                acc[i][j] = __builtin_amdgcn_mfma_f32_16x16x32_bf16(af[i], bfv[j], acc[i][j], 0, 0, 0);
    }

    float fs[4];
#pragma unroll
    for (int j = 0; j < 4; ++j) fs[j] = fsq[n0 + wn * 64 + j * 16 + col];
#pragma unroll
    for (int i = 0; i < 4; ++i) {
#pragma unroll
        for (int r = 0; r < 4; ++r) {
            const int mrow = wm * 64 + i * 16 + quad * 4 + r;
            const float qs = qsq[m0 + mrow];
            float mn = 3.0e38f;
#pragma unroll
            for (int j = 0; j < 4; ++j) {
                float d2 = qs + fs[j] - 2.0f * acc[i][j][r];
                mn = fminf(mn, fmaxf(d2, 0.0f));
            }
#pragma unroll
            for (int off = 1; off < 16; off <<= 1) mn = fminf(mn, __shfl_xor(mn, off, 64));
            if (col == 0) smin[mrow * 2 + wn] = mn;
        }
    }
    __syncthreads();
    if (tid < 128) {
        float v = fminf(smin[tid * 2 + 0], smin[tid * 2 + 1]);
        atomicMin(outbits + m0 + tid, __float_as_uint(v));
    }
}

// Emergency path (tiny ws)
__global__ __launch_bounds__(256)
void tier3_kernel(const float* __restrict__ rel, const float* __restrict__ a1,
                  const float* __restrict__ a2, const float* __restrict__ fr,
                  const float* __restrict__ fa1, const float* __restrict__ fa2,
                  unsigned int* __restrict__ outbits) {
    __shared__ float qs[16][384];
    __shared__ float red[4][16];
    const int tid = threadIdx.x;
    const int qbase = blockIdx.y * 16;
    const int fbase = blockIdx.x * 2048;
    for (int i = tid; i < 16 * 384; i += 256) {
        int r = i / 384, c = i % 384;
        const float* src = (c < 128) ? rel : (c < 256) ? a1 : a2;
        qs[r][c] = src[(size_t)(qbase + r) * 128 + (c & 127)];
    }
    __syncthreads();
    float mn[16];
#pragma unroll
    for (int q = 0; q < 16; ++q) mn[q] = 3.0e38f;
    for (int fi = 0; fi < 2048; fi += 256) {
        const int f = fbase + fi + tid;
        float acc[16];
#pragma unroll
        for (int q = 0; q < 16; ++q) acc[q] = 0.f;
#pragma unroll
        for (int p = 0; p < 3; ++p) {
            const float* fp = ((p == 0) ? fr : (p == 1) ? fa1 : fa2) + (size_t)f * 128;
            for (int k4 = 0; k4 < 32; ++k4) {
                const float4 fv = *(const float4*)(fp + k4 * 4);
#pragma unroll
                for (int q = 0; q < 16; ++q) {
                    float d0 = fv.x - qs[q][p * 128 + k4 * 4 + 0];
                    float d1 = fv.y - qs[q][p * 128 + k4 * 4 + 1];
                    float d2 = fv.z - qs[q][p * 128 + k4 * 4 + 2];
                    float d3 = fv.w - qs[q][p * 128 + k4 * 4 + 3];
                    acc[q] += d0 * d0 + d1 * d1 + d2 * d2 + d3 * d3;
                }
            }
        }
#pragma unroll
        for (int q = 0; q < 16; ++q) mn[q] = fminf(mn[q], fmaxf(acc[q], 0.f));
    }
#pragma unroll
    for (int q = 0; q < 16; ++q) {
        float v = mn[q];
#pragma unroll
        for (int off = 32; off >= 1; off >>= 1) v = fminf(v, __shfl_xor(v, off, 64));
        if ((tid & 63) == 0) red[tid >> 6][q] = v;
    }
    __syncthreads();
    if (tid < 16) {
        float v = fminf(fminf(red[0][tid], red[1][tid]), fminf(red[2][tid], red[3][tid]));
        atomicMin(outbits + qbase + tid, __float_as_uint(v));
    }
}

extern "C" void kernel_launch(void* const* d_in, const int* in_sizes, int n_in,
                              void* d_out, int out_size, void* d_ws, size_t ws_size,
                              hipStream_t stream) {
    const float* rel = (const float*)d_in[0];
    const float* a1 = (const float*)d_in[1];
    const float* a2 = (const float*)d_in[2];
    const float* fr = (const float*)d_in[3];
    const float* fa1 = (const float*)d_in[4];
    const float* fa2 = (const float*)d_in[5];

    const int E = 128, K = 384;
    const int B = in_sizes[0] / E;   // 2048
    const int F = in_sizes[3] / E;   // 65536

    float* out = (float*)d_out;
    unsigned int* outbits = (unsigned int*)d_out;

    const size_t fb_bytes = (size_t)F * K * 2;
    const size_t qb_bytes = (size_t)B * K * 2;
    const size_t need_full = fb_bytes + qb_bytes + (size_t)F * 4 + (size_t)B * 4;
    const size_t need_lean = qb_bytes + (size_t)F * 4 + (size_t)B * 4;

    init_min_kernel<<<(B + 255) / 256, 256, 0, stream>>>(outbits, B);

    const bool shapes_ok = (B % 128 == 0) && (F % 2048 == 0);
    if (ws_size >= need_full && shapes_ok) {
        unsigned short* Fb = (unsigned short*)d_ws;
        unsigned short* Qb = (unsigned short*)((char*)d_ws + fb_bytes);
        float* fsq = (float*)((char*)d_ws + fb_bytes + qb_bytes);
        float* qsq = fsq + F;
        conv_swz_kernel<<<B / 4, 256, 0, stream>>>(rel, a1, a2, Qb, qsq, B);
        conv_swz_kernel<<<F / 4, 256, 0, stream>>>(fr, fa1, fa2, Fb, fsq, F);
        // grid: x = n-groups (8 tiles of 256 each), y = m-tiles -> 512 WGs @ 2/CU
        gemm_full_kernel<<<dim3(F / 2048, B / 128), 256, 0, stream>>>(
            Qb, Fb, qsq, fsq, outbits, 8);
    } else if (ws_size >= need_lean && B % 128 == 0 && F % 128 == 0) {
        unsigned short* Qb = (unsigned short*)d_ws;
        float* fsq = (float*)((char*)d_ws + qb_bytes);
        float* qsq = fsq + F;
        conv_rows_kernel<<<B / 4, 256, 0, stream>>>(rel, a1, a2, Qb, qsq, B);
        conv_rows_kernel<<<F / 4, 256, 0, stream>>>(fr, fa1, fa2, nullptr, fsq, F);
        gemm_lean_kernel<<<dim3(B / 128, F / 128), 256, 0, stream>>>(
            Qb, fr, fa1, fa2, qsq, fsq, outbits, K);
    } else {
        tier3_kernel<<<dim3(F / 2048, B / 16), 256, 0, stream>>>(rel, a1, a2, fr, fa1, fa2, outbits);
    }

    finalize_kernel<<<(B + 255) / 256, 256, 0, stream>>>(out, B);
}